// Round 1
// 507.894 us; speedup vs baseline: 1.0784x; 1.0784x over previous
//
#include <hip/hip_runtime.h>
#include <hip/hip_bf16.h>
#include <cstdint>
#include <cstddef>

// ---------------------------------------------------------------------------
// CacheShrinkMLAAttention (T=2048, D_MODEL=4096, 32 q-heads, 4 compressed KV
// heads, D_HEAD=128). Live dataflow only:
//   q = rope(hidden@Wq)*scale ; c_kv = hidden@Wc ; flash-GQA over c_k/c_v ;
//   out = ctx@Wo.   (Wuk/Wuv decompression is dead in the reference.)
// Storage: fp32 in/out. Internals: bf16 MFMA, fp32 accumulate.
// R5: GEMM BK 32->64 (two 32-wide LDS panels: half the barrier crossings,
// rows stay 64B so ds_read_b128 conflicts stay 8-way, not 16-way).
// EPI=3 split-K/atomicAdd dropped -> direct fp32 store, no memset
// (removes 64MB RMW + 32MB memset; grid 512 = 2 blocks/CU uniform).
// ---------------------------------------------------------------------------

typedef unsigned short u16;
typedef short s16x8 __attribute__((ext_vector_type(8)));
typedef short s16x4 __attribute__((ext_vector_type(4)));
typedef float f32x4 __attribute__((ext_vector_type(4)));

#define MFMA16(a, b, c) __builtin_amdgcn_mfma_f32_16x16x32_bf16((a), (b), (c), 0, 0, 0)

// 1/sqrt(128) * log2(e): folded into q at rope time; attention uses exp2.
#define QSCALE 0.12751899f
// log2(10000)
#define LOG2_ROPE_BASE 13.287712379549449f
// fixed softmax max (exp2 domain) — exact (no overflow for any plausible score)
#define FIXMAX 24.0f

__device__ __forceinline__ u16 f2b(float f) {
  return __builtin_bit_cast(u16, __float2bfloat16(f));
}
__device__ __forceinline__ void async_copy16(u16* lds, const u16* g) {
  __builtin_amdgcn_global_load_lds(
      (const __attribute__((address_space(1))) unsigned int*)g,
      (__attribute__((address_space(3))) unsigned int*)lds, 16, 0, 0);
}

// ---------------------------------------------------------------------------
// Fused prep: one launch does hidden fp32->bf16 convert + Wq/Wc/Wo
// fp32->bf16 transposes. Linear grid, decoded per job:
//   [0,4096)            : Wq  tp  (64x64 tiles, 64x64 grid)
//   [4096,5120)         : Wc  tp  (16x64 grid)
//   [5120,9216)         : Wo  tp  (64x64 grid)
//   [9216,13312)        : hidden convert (8 elems/thread)
// ---------------------------------------------------------------------------
__global__ __launch_bounds__(256)
void prep_kernel(const float* __restrict__ hidden, const float* __restrict__ Wq,
                 const float* __restrict__ Wc, const float* __restrict__ Wo,
                 u16* __restrict__ hb, u16* __restrict__ WqT,
                 u16* __restrict__ WcT, u16* __restrict__ WoT) {
  __shared__ alignas(16) u16 tile[64 * 72];
  const int b = blockIdx.x;
  const int t = threadIdx.x;

  if (b >= 9216) {  // hidden convert
    int i = (b - 9216) * 256 + t;
    const float4* p = (const float4*)hidden + (size_t)i * 2;
    float4 a = p[0], c = p[1];
    s16x8 v;
    v[0] = (short)f2b(a.x); v[1] = (short)f2b(a.y);
    v[2] = (short)f2b(a.z); v[3] = (short)f2b(a.w);
    v[4] = (short)f2b(c.x); v[5] = (short)f2b(c.y);
    v[6] = (short)f2b(c.z); v[7] = (short)f2b(c.w);
    *(s16x8*)&hb[(size_t)i * 8] = v;
    return;
  }

  const float* in;
  u16* out;
  int gx, in_ld, out_ld;
  if (b < 4096)      { in = Wq; out = WqT; gx = b;        in_ld = 4096; out_ld = 4096; }
  else if (b < 5120) { in = Wc; out = WcT; gx = b - 4096; in_ld = 1024; out_ld = 4096; }
  else               { in = Wo; out = WoT; gx = b - 5120; in_ld = 4096; out_ld = 4096; }
  const int nbx = in_ld / 64;
  const int c0 = (gx % nbx) * 64, r0 = (gx / nbx) * 64;
  const int rr = t >> 3, cc = (t & 7) * 8;
#pragma unroll
  for (int p = 0; p < 2; p++) {
    int row = p * 32 + rr;
    const float4* src = (const float4*)&in[(size_t)(r0 + row) * in_ld + c0 + cc];
    float4 a = src[0], c = src[1];
    s16x8 v;
    v[0] = (short)f2b(a.x); v[1] = (short)f2b(a.y);
    v[2] = (short)f2b(a.z); v[3] = (short)f2b(a.w);
    v[4] = (short)f2b(c.x); v[5] = (short)f2b(c.y);
    v[6] = (short)f2b(c.z); v[7] = (short)f2b(c.w);
    *(s16x8*)&tile[row * 72 + cc] = v;
  }
  __syncthreads();
#pragma unroll
  for (int p = 0; p < 2; p++) {
    int orow = p * 32 + rr;
    s16x8 v;
#pragma unroll
    for (int j = 0; j < 8; j++) v[j] = (short)tile[(cc + j) * 72 + orow];
    *(s16x8*)&out[(size_t)(c0 + orow) * out_ld + r0 + cc] = v;
  }
}

// ---------------------------------------------------------------------------
// bf16 64x64 tile transpose for ckv->V^T, all 4 kv heads in one launch.
// out[kh][c][r] = in[r][512 + kh*128 + c]
// ---------------------------------------------------------------------------
__global__ __launch_bounds__(256)
void transpose_ckv(const u16* __restrict__ in, u16* __restrict__ out) {
  __shared__ alignas(16) u16 tile[64 * 72];
  const int kh = blockIdx.z;
  const int c0 = blockIdx.x * 64, r0 = blockIdx.y * 64;
  const int in_off = 512 + kh * 128;
  u16* outk = out + (size_t)kh * 128 * 2048;
  const int t = threadIdx.x;
  const int rr = t >> 3, cc = (t & 7) * 8;
#pragma unroll
  for (int p = 0; p < 2; p++) {
    int row = p * 32 + rr;
    s16x8 v = *(const s16x8*)&in[(size_t)(r0 + row) * 1024 + in_off + c0 + cc];
    *(s16x8*)&tile[row * 72 + cc] = v;
  }
  __syncthreads();
#pragma unroll
  for (int p = 0; p < 2; p++) {
    int orow = p * 32 + rr;
    s16x8 v;
#pragma unroll
    for (int j = 0; j < 8; j++) v[j] = (short)tile[(cc + j) * 72 + orow];
    *(s16x8*)&outk[(size_t)(c0 + orow) * 2048 + r0 + cc] = v;
  }
}

// ---------------------------------------------------------------------------
// GEMM: C = A(Mx4096,row) * Bt(Nx4096,row)^T, bf16 in, fp32 acc.
// 128x128 block tile, BK=64 staged as TWO 32-wide panels (64B LDS rows ->
// 8-way ds_read conflict, not 16-way), 4 waves (2x2), 4x4 MFMA tiles/wave.
// Column remap: acc tile j covers cols wn*32+(j&1)*16+(j>>1)*64 so RoPE
// pairs (d, d+64) are acc[i][j]/acc[i][j+2] in the SAME lane.
// EPI=1 (fused q/ckv): n0<4096 -> in-register Neox RoPE + QSCALE -> Cv;
//   n0>=4096 -> plain bf16 -> Cv2 (stride 1024).
// EPI=3: plain fp32 store -> Cv (full K per block, no split-K/atomics).
// LDS 32KB -> 3 blocks/CU possible; grids here give 2-3/CU residency.
// ---------------------------------------------------------------------------
template <int EPI>
__global__ __launch_bounds__(256, 3)
void gemm_bt(const u16* __restrict__ A, const u16* __restrict__ Bt,
             void* __restrict__ Cv, void* __restrict__ Cv2,
             const int* __restrict__ positions) {
  __shared__ alignas(16) u16 As[2][128 * 32];
  __shared__ alignas(16) u16 Bs[2][128 * 32];

  const int tid = threadIdx.x;
  const int w = tid >> 6, l = tid & 63;
  const int wm = w >> 1, wn = w & 1;
  const int lrow = l >> 4, lcol = l & 15;
  const int m0 = blockIdx.y * 128, n0 = blockIdx.x * 128;

  f32x4 acc[4][4] = {};

  const int srow = l >> 2;            // 0..15 row within a 16-row issue
  const int scol = (l & 3) * 8;       // elem offset within 32-elem row
  const u16* Ag = A + (size_t)(m0 + w * 32 + srow) * 4096 + scol;
  const u16* Bg = Bt + (size_t)(n0 + w * 32 + srow) * 4096 + scol;

  for (int kt = 0; kt < 4096; kt += 64) {
    __syncthreads();
#pragma unroll
    for (int hf = 0; hf < 2; hf++) {
      async_copy16(&As[hf][(w * 32) * 32], Ag + kt + hf * 32);
      async_copy16(&As[hf][(w * 32 + 16) * 32],
                   Ag + (size_t)16 * 4096 + kt + hf * 32);
      async_copy16(&Bs[hf][(w * 32) * 32], Bg + kt + hf * 32);
      async_copy16(&Bs[hf][(w * 32 + 16) * 32],
                   Bg + (size_t)16 * 4096 + kt + hf * 32);
    }
    __syncthreads();

#pragma unroll
    for (int hf = 0; hf < 2; hf++) {
      s16x8 a[4], b[4];
#pragma unroll
      for (int i = 0; i < 4; i++)
        a[i] = *(const s16x8*)&As[hf][(wm * 64 + i * 16 + lcol) * 32 + lrow * 8];
#pragma unroll
      for (int j = 0; j < 4; j++)
        b[j] = *(const s16x8*)&Bs[hf][(wn * 32 + (j & 1) * 16 + (j >> 1) * 64 +
                                       lcol) * 32 + lrow * 8];
#pragma unroll
      for (int i = 0; i < 4; i++)
#pragma unroll
        for (int j = 0; j < 4; j++)
          acc[i][j] = MFMA16(a[i], b[j], acc[i][j]);
    }
  }

  if constexpr (EPI == 3) {
    float* C = (float*)Cv;
#pragma unroll
    for (int i = 0; i < 4; i++) {
      int row = m0 + wm * 64 + i * 16 + lrow * 4;
#pragma unroll
      for (int j = 0; j < 4; j++) {
        int col = n0 + wn * 32 + (j & 1) * 16 + (j >> 1) * 64 + lcol;
#pragma unroll
        for (int r = 0; r < 4; r++)
          C[(size_t)(row + r) * 4096 + col] = acc[i][j][r];
      }
    }
  } else {
    if (n0 >= 4096) {
      u16* C = (u16*)Cv2;
      int cb = n0 - 4096;
#pragma unroll
      for (int i = 0; i < 4; i++) {
        int row = m0 + wm * 64 + i * 16 + lrow * 4;
#pragma unroll
        for (int j = 0; j < 4; j++) {
          int col = cb + wn * 32 + (j & 1) * 16 + (j >> 1) * 64 + lcol;
#pragma unroll
          for (int r = 0; r < 4; r++)
            C[(size_t)(row + r) * 1024 + col] = f2b(acc[i][j][r]);
        }
      }
    } else {
      // In-register Neox RoPE: pair (d, d+64) = (acc[i][j], acc[i][j+2]).
      u16* C = (u16*)Cv;
      float inv[2];
#pragma unroll
      for (int j = 0; j < 2; j++) {
        int d = wn * 32 + j * 16 + lcol;
        inv[j] = exp2f((float)d * (-LOG2_ROPE_BASE / 64.f));
      }
#pragma unroll
      for (int i = 0; i < 4; i++) {
        int row = m0 + wm * 64 + i * 16 + lrow * 4;
#pragma unroll
        for (int r = 0; r < 4; r++) {
          float pos = (float)positions[row + r];
#pragma unroll
          for (int j = 0; j < 2; j++) {
            int d = wn * 32 + j * 16 + lcol;
            float ang = pos * inv[j];
            float sv, cv;
            sincosf(ang, &sv, &cv);
            float x1 = acc[i][j][r];
            float x2 = acc[i][j + 2][r];
            C[(size_t)(row + r) * 4096 + n0 + d] = f2b((x1 * cv - x2 * sv) * QSCALE);
            C[(size_t)(row + r) * 4096 + n0 + d + 64] =
                f2b((x2 * cv + x1 * sv) * QSCALE);
          }
        }
      }
    }
  }
}

// ---------------------------------------------------------------------------
// Flash GQA attention over the compressed cache (bf16 in/out, fp32 acc).
// Block: 128 q-rows x 1 head (4 waves x 32 q). Key tile = 64.
// S^T = K*Q^T; P->A-layout via contiguous wave-private LDS; fixed-max
// exp2 softmax (no running max / rescale / per-iter barrier).
// ---------------------------------------------------------------------------
__global__ __launch_bounds__(256, 3)
void attn_kernel(const u16* __restrict__ Q, const u16* __restrict__ ckv,
                 const u16* __restrict__ vT, u16* __restrict__ ctx) {
  __shared__ alignas(16) u16 S0[16384];   // 32KB: Q stage; then K|V tiles
  __shared__ alignas(16) u16 Ps[4][4096]; // 16KB: per-wave P [2 panels][32 q][32 k]
  __shared__ alignas(16) float red[4][32];

  const int tid = threadIdx.x, w = tid >> 6, l = tid & 63;
  const int lrow = l >> 4, lcol = l & 15;
  const int qt = (int)gridDim.x - 1 - (int)blockIdx.x;  // heavy blocks first
  const int h = blockIdx.y, kh = h >> 3;
  const int q0w = w * 32;

  {
    const u16* qg = Q + (size_t)(qt * 128 + w * 32 + lrow) * 4096 + h * 128 + lcol * 8;
#pragma unroll
    for (int is = 0; is < 8; is++)
      async_copy16(&S0[(w * 32 + is * 4) * 128], qg + (size_t)is * 4 * 4096);
  }
  __syncthreads();
  s16x8 qf[2][4];
#pragma unroll
  for (int nt = 0; nt < 2; nt++)
#pragma unroll
    for (int kc = 0; kc < 4; kc++)
      qf[nt][kc] =
          *(const s16x8*)&S0[(q0w + nt * 16 + lcol) * 128 + kc * 32 + lrow * 8];

  u16* Kt = S0;          // [4 panels][64 keys][32 d] = 16KB
  u16* Vt = S0 + 8192;   // [2 panels][128 d][32 keys] = 16KB

  f32x4 o[2][8] = {};
  float l_run[2] = {0.f, 0.f};

  const int nkt = 2 * (qt + 1);
  for (int kt = 0; kt < nkt; kt++) {
    __syncthreads();
    {
      const u16* kg =
          ckv + (size_t)(kt * 64 + w * 16 + (l >> 2)) * 1024 + kh * 128 + (l & 3) * 8;
#pragma unroll
      for (int kc = 0; kc < 4; kc++)
        async_copy16(&Kt[kc * 2048 + (w * 16) * 32], kg + kc * 32);
      const u16* vg =
          vT + (size_t)(kh * 128 + w * 32 + (l >> 2)) * 2048 + kt * 64 + (l & 3) * 8;
#pragma unroll
      for (int kc = 0; kc < 2; kc++) {
        async_copy16(&Vt[kc * 4096 + (w * 32) * 32], vg + kc * 32);
        async_copy16(&Vt[kc * 4096 + (w * 32 + 16) * 32],
                     vg + (size_t)16 * 2048 + kc * 32);
      }
    }
    __syncthreads();

    f32x4 s[4][2] = {};
#pragma unroll
    for (int kc = 0; kc < 4; kc++)
#pragma unroll
      for (int mt = 0; mt < 4; mt++) {
        s16x8 ka = *(const s16x8*)&Kt[kc * 2048 + (mt * 16 + lcol) * 32 + lrow * 8];
        s[mt][0] = MFMA16(ka, qf[0][kc], s[mt][0]);
        s[mt][1] = MFMA16(ka, qf[1][kc], s[mt][1]);
      }

    if (kt >= 2 * qt) {  // diagonal 128-block: causal mask
      int koff = (kt & 1) * 64;
#pragma unroll
      for (int mt = 0; mt < 4; mt++)
#pragma unroll
        for (int nt = 0; nt < 2; nt++)
#pragma unroll
          for (int r = 0; r < 4; r++) {
            int key = koff + mt * 16 + lrow * 4 + r;
            int q = q0w + nt * 16 + lcol;
            if (key > q) s[mt][nt][r] = -1e30f;
          }
    }

#pragma unroll
    for (int nt = 0; nt < 2; nt++) {
      float sum = 0.f;
#pragma unroll
      for (int mt = 0; mt < 4; mt++) {
        s16x4 pk;
#pragma unroll
        for (int r = 0; r < 4; r++) {
          float p = exp2f(s[mt][nt][r] - FIXMAX);
          sum += p;
          pk[r] = (short)f2b(p);
        }
        int key = mt * 16 + lrow * 4;
        *(s16x4*)&Ps[w][(key >> 5) * 2048 + (nt * 16 + lcol) * 32 + (key & 31)] = pk;
      }
      sum += __shfl_xor(sum, 16);
      sum += __shfl_xor(sum, 32);
      l_run[nt] += sum;
    }
    // no barrier: Ps[w] is wave-private; HW lgkmcnt orders write->read.

#pragma unroll
    for (int kc = 0; kc < 2; kc++) {
      s16x8 pa0 = *(const s16x8*)&Ps[w][kc * 2048 + lcol * 32 + lrow * 8];
      s16x8 pa1 = *(const s16x8*)&Ps[w][kc * 2048 + (16 + lcol) * 32 + lrow * 8];
#pragma unroll
      for (int ntO = 0; ntO < 8; ntO++) {
        s16x8 vb = *(const s16x8*)&Vt[kc * 4096 + (ntO * 16 + lcol) * 32 + lrow * 8];
        o[0][ntO] = MFMA16(pa0, vb, o[0][ntO]);
        o[1][ntO] = MFMA16(pa1, vb, o[1][ntO]);
      }
    }
  }

  if (l < 16) {
    red[w][l] = 1.f / l_run[0];
    red[w][16 + l] = 1.f / l_run[1];
  }
  __syncthreads();
  f32x4 lf0 = *(const f32x4*)&red[w][lrow * 4];
  f32x4 lf1 = *(const f32x4*)&red[w][16 + lrow * 4];
#pragma unroll
  for (int mtO = 0; mtO < 2; mtO++)
#pragma unroll
    for (int ntO = 0; ntO < 8; ntO++)
#pragma unroll
      for (int r = 0; r < 4; r++) {
        float lv = mtO ? lf1[r] : lf0[r];
        int q = qt * 128 + q0w + mtO * 16 + lrow * 4 + r;
        int d = h * 128 + ntO * 16 + lcol;
        ctx[(size_t)q * 4096 + d] = f2b(o[mtO][ntO][r] * lv);
      }
}

// ---------------------------------------------------------------------------
extern "C" void kernel_launch(void* const* d_in, const int* in_sizes, int n_in,
                              void* d_out, int out_size, void* d_ws, size_t ws_size,
                              hipStream_t stream) {
  const int* positions = (const int*)d_in[0];
  const float* hidden = (const float*)d_in[1];  // (2048, 4096) fp32
  const float* Wq = (const float*)d_in[2];      // (4096, 4096) fp32
  const float* Wc = (const float*)d_in[3];      // (4096, 1024) fp32
  // d_in[4] (Wuk), d_in[5] (Wuv): dead in the reference -> skipped entirely.
  const float* Wo = (const float*)d_in[6];      // (4096, 4096) fp32

  char* ws = (char*)d_ws;
  u16* hb  = (u16*)(ws);                  // 16,777,216 B : bf16 hidden; later ctx
  u16* WT  = (u16*)(ws + 16777216);       // 41,943,040 B : [WqT;WcT] 5120x4096
  u16* qbf = (u16*)(ws + 58720256);       // 16,777,216 B : rope(q)*scale (bf16)
  u16* ckv = (u16*)(ws + 75497472);       //  4,194,304 B : c_kv bf16
  u16* cvT = (u16*)(ws + 79691776);       //  2,097,152 B : V^T [4][128][2048] bf16
  u16* WoT = (u16*)(ws + 81788928);       // 33,554,432 B : Wo^T bf16
  u16* ctx = hb;                          // reuse: hidden dead after fused GEMM

  dim3 blk(256);

  // one prep launch: hidden convert + Wq/Wc/Wo fp32->bf16 transposes
  prep_kernel<<<dim3(13312), blk, 0, stream>>>(hidden, Wq, Wc, Wo, hb, WT,
                                               WT + (size_t)4096 * 4096, WoT);

  // fused: q = rope(hidden@Wq)*scale -> qbf ; c_kv = hidden@Wc -> ckv
  gemm_bt<1><<<dim3(40, 16), blk, 0, stream>>>(hb, WT, qbf, ckv, positions);

  // V^T per kv head: cvT[kh][d][t] = ckv[t][512 + kh*128 + d]
  transpose_ckv<<<dim3(2, 32, 4), blk, 0, stream>>>(ckv, cvT);

  // flash GQA attention -> ctx (T, 4096) bf16 (overwrites hb; hidden is dead)
  attn_kernel<<<dim3(16, 32), blk, 0, stream>>>(qbf, ckv, cvT, ctx);

  // out = ctx@Wo -> fp32 d_out, direct store (512 blocks, full K per block)
  gemm_bt<3><<<dim3(32, 16), blk, 0, stream>>>(ctx, WoT, d_out, nullptr,
                                               positions);
}

// Round 2
// 482.815 us; speedup vs baseline: 1.1344x; 1.0519x over previous
//
#include <hip/hip_runtime.h>
#include <hip/hip_bf16.h>
#include <cstdint>
#include <cstddef>

// ---------------------------------------------------------------------------
// CacheShrinkMLAAttention (T=2048, D_MODEL=4096, 32 q-heads, 4 compressed KV
// heads, D_HEAD=128). Live dataflow only:
//   q = rope(hidden@Wq)*scale ; c_kv = hidden@Wc ; flash-GQA over c_k/c_v ;
//   out = ctx@Wo.   (Wuk/Wuv decompression is dead in the reference.)
// Storage: fp32 in/out. Internals: bf16 MFMA, fp32 accumulate.
// R6: attention rewritten for causal load balance — each block processes the
// q-tile PAIR (15-x, x) sequentially (uniform 34 key-tiles/block, grid 256 =
// 1 block/CU; old grid put same-qt blocks on one CU -> 2x imbalance).
// K/V double-buffered (2-phase, vmcnt(0)+barrier once per tile); Q fragments
// loaded straight to registers (no LDS stage). T2 XOR swizzle (16B slot ^=
// (row>>1)&3) on K/V (via pre-swizzled global source; global_load_lds dest
// must stay linear) and on Ps write+read — kills the 8-way ds_read conflicts
// (13.3M conflict cycles in R5).
// ---------------------------------------------------------------------------

typedef unsigned short u16;
typedef short s16x8 __attribute__((ext_vector_type(8)));
typedef short s16x4 __attribute__((ext_vector_type(4)));
typedef float f32x4 __attribute__((ext_vector_type(4)));

#define MFMA16(a, b, c) __builtin_amdgcn_mfma_f32_16x16x32_bf16((a), (b), (c), 0, 0, 0)

// 1/sqrt(128) * log2(e): folded into q at rope time; attention uses exp2.
#define QSCALE 0.12751899f
// log2(10000)
#define LOG2_ROPE_BASE 13.287712379549449f
// fixed softmax max (exp2 domain) — exact (no overflow for any plausible score)
#define FIXMAX 24.0f

__device__ __forceinline__ u16 f2b(float f) {
  return __builtin_bit_cast(u16, __float2bfloat16(f));
}
__device__ __forceinline__ void async_copy16(u16* lds, const u16* g) {
  __builtin_amdgcn_global_load_lds(
      (const __attribute__((address_space(1))) unsigned int*)g,
      (__attribute__((address_space(3))) unsigned int*)lds, 16, 0, 0);
}

// ---------------------------------------------------------------------------
// Fused prep: one launch does hidden fp32->bf16 convert + Wq/Wc/Wo
// fp32->bf16 transposes. Linear grid, decoded per job:
//   [0,4096)            : Wq  tp  (64x64 tiles, 64x64 grid)
//   [4096,5120)         : Wc  tp  (16x64 grid)
//   [5120,9216)         : Wo  tp  (64x64 grid)
//   [9216,13312)        : hidden convert (8 elems/thread)
// ---------------------------------------------------------------------------
__global__ __launch_bounds__(256)
void prep_kernel(const float* __restrict__ hidden, const float* __restrict__ Wq,
                 const float* __restrict__ Wc, const float* __restrict__ Wo,
                 u16* __restrict__ hb, u16* __restrict__ WqT,
                 u16* __restrict__ WcT, u16* __restrict__ WoT) {
  __shared__ alignas(16) u16 tile[64 * 72];
  const int b = blockIdx.x;
  const int t = threadIdx.x;

  if (b >= 9216) {  // hidden convert
    int i = (b - 9216) * 256 + t;
    const float4* p = (const float4*)hidden + (size_t)i * 2;
    float4 a = p[0], c = p[1];
    s16x8 v;
    v[0] = (short)f2b(a.x); v[1] = (short)f2b(a.y);
    v[2] = (short)f2b(a.z); v[3] = (short)f2b(a.w);
    v[4] = (short)f2b(c.x); v[5] = (short)f2b(c.y);
    v[6] = (short)f2b(c.z); v[7] = (short)f2b(c.w);
    *(s16x8*)&hb[(size_t)i * 8] = v;
    return;
  }

  const float* in;
  u16* out;
  int gx, in_ld, out_ld;
  if (b < 4096)      { in = Wq; out = WqT; gx = b;        in_ld = 4096; out_ld = 4096; }
  else if (b < 5120) { in = Wc; out = WcT; gx = b - 4096; in_ld = 1024; out_ld = 4096; }
  else               { in = Wo; out = WoT; gx = b - 5120; in_ld = 4096; out_ld = 4096; }
  const int nbx = in_ld / 64;
  const int c0 = (gx % nbx) * 64, r0 = (gx / nbx) * 64;
  const int rr = t >> 3, cc = (t & 7) * 8;
#pragma unroll
  for (int p = 0; p < 2; p++) {
    int row = p * 32 + rr;
    const float4* src = (const float4*)&in[(size_t)(r0 + row) * in_ld + c0 + cc];
    float4 a = src[0], c = src[1];
    s16x8 v;
    v[0] = (short)f2b(a.x); v[1] = (short)f2b(a.y);
    v[2] = (short)f2b(a.z); v[3] = (short)f2b(a.w);
    v[4] = (short)f2b(c.x); v[5] = (short)f2b(c.y);
    v[6] = (short)f2b(c.z); v[7] = (short)f2b(c.w);
    *(s16x8*)&tile[row * 72 + cc] = v;
  }
  __syncthreads();
#pragma unroll
  for (int p = 0; p < 2; p++) {
    int orow = p * 32 + rr;
    s16x8 v;
#pragma unroll
    for (int j = 0; j < 8; j++) v[j] = (short)tile[(cc + j) * 72 + orow];
    *(s16x8*)&out[(size_t)(c0 + orow) * out_ld + r0 + cc] = v;
  }
}

// ---------------------------------------------------------------------------
// bf16 64x64 tile transpose for ckv->V^T, all 4 kv heads in one launch.
// out[kh][c][r] = in[r][512 + kh*128 + c]
// ---------------------------------------------------------------------------
__global__ __launch_bounds__(256)
void transpose_ckv(const u16* __restrict__ in, u16* __restrict__ out) {
  __shared__ alignas(16) u16 tile[64 * 72];
  const int kh = blockIdx.z;
  const int c0 = blockIdx.x * 64, r0 = blockIdx.y * 64;
  const int in_off = 512 + kh * 128;
  u16* outk = out + (size_t)kh * 128 * 2048;
  const int t = threadIdx.x;
  const int rr = t >> 3, cc = (t & 7) * 8;
#pragma unroll
  for (int p = 0; p < 2; p++) {
    int row = p * 32 + rr;
    s16x8 v = *(const s16x8*)&in[(size_t)(r0 + row) * 1024 + in_off + c0 + cc];
    *(s16x8*)&tile[row * 72 + cc] = v;
  }
  __syncthreads();
#pragma unroll
  for (int p = 0; p < 2; p++) {
    int orow = p * 32 + rr;
    s16x8 v;
#pragma unroll
    for (int j = 0; j < 8; j++) v[j] = (short)tile[(cc + j) * 72 + orow];
    *(s16x8*)&outk[(size_t)(c0 + orow) * 2048 + r0 + cc] = v;
  }
}

// ---------------------------------------------------------------------------
// GEMM: C = A(Mx4096,row) * Bt(Nx4096,row)^T, bf16 in, fp32 acc.
// 128x128 block tile, BK=64 staged as TWO 32-wide panels (64B LDS rows ->
// 8-way ds_read conflict, not 16-way), 4 waves (2x2), 4x4 MFMA tiles/wave.
// Column remap: acc tile j covers cols wn*32+(j&1)*16+(j>>1)*64 so RoPE
// pairs (d, d+64) are acc[i][j]/acc[i][j+2] in the SAME lane.
// EPI=1 (fused q/ckv): n0<4096 -> in-register Neox RoPE + QSCALE -> Cv;
//   n0>=4096 -> plain bf16 -> Cv2 (stride 1024).
// EPI=3: plain fp32 store -> Cv (full K per block, no split-K/atomics).
// ---------------------------------------------------------------------------
template <int EPI>
__global__ __launch_bounds__(256, 3)
void gemm_bt(const u16* __restrict__ A, const u16* __restrict__ Bt,
             void* __restrict__ Cv, void* __restrict__ Cv2,
             const int* __restrict__ positions) {
  __shared__ alignas(16) u16 As[2][128 * 32];
  __shared__ alignas(16) u16 Bs[2][128 * 32];

  const int tid = threadIdx.x;
  const int w = tid >> 6, l = tid & 63;
  const int wm = w >> 1, wn = w & 1;
  const int lrow = l >> 4, lcol = l & 15;
  const int m0 = blockIdx.y * 128, n0 = blockIdx.x * 128;

  f32x4 acc[4][4] = {};

  const int srow = l >> 2;            // 0..15 row within a 16-row issue
  const int scol = (l & 3) * 8;       // elem offset within 32-elem row
  const u16* Ag = A + (size_t)(m0 + w * 32 + srow) * 4096 + scol;
  const u16* Bg = Bt + (size_t)(n0 + w * 32 + srow) * 4096 + scol;

  for (int kt = 0; kt < 4096; kt += 64) {
    __syncthreads();
#pragma unroll
    for (int hf = 0; hf < 2; hf++) {
      async_copy16(&As[hf][(w * 32) * 32], Ag + kt + hf * 32);
      async_copy16(&As[hf][(w * 32 + 16) * 32],
                   Ag + (size_t)16 * 4096 + kt + hf * 32);
      async_copy16(&Bs[hf][(w * 32) * 32], Bg + kt + hf * 32);
      async_copy16(&Bs[hf][(w * 32 + 16) * 32],
                   Bg + (size_t)16 * 4096 + kt + hf * 32);
    }
    __syncthreads();

#pragma unroll
    for (int hf = 0; hf < 2; hf++) {
      s16x8 a[4], b[4];
#pragma unroll
      for (int i = 0; i < 4; i++)
        a[i] = *(const s16x8*)&As[hf][(wm * 64 + i * 16 + lcol) * 32 + lrow * 8];
#pragma unroll
      for (int j = 0; j < 4; j++)
        b[j] = *(const s16x8*)&Bs[hf][(wn * 32 + (j & 1) * 16 + (j >> 1) * 64 +
                                       lcol) * 32 + lrow * 8];
#pragma unroll
      for (int i = 0; i < 4; i++)
#pragma unroll
        for (int j = 0; j < 4; j++)
          acc[i][j] = MFMA16(a[i], b[j], acc[i][j]);
    }
  }

  if constexpr (EPI == 3) {
    float* C = (float*)Cv;
#pragma unroll
    for (int i = 0; i < 4; i++) {
      int row = m0 + wm * 64 + i * 16 + lrow * 4;
#pragma unroll
      for (int j = 0; j < 4; j++) {
        int col = n0 + wn * 32 + (j & 1) * 16 + (j >> 1) * 64 + lcol;
#pragma unroll
        for (int r = 0; r < 4; r++)
          C[(size_t)(row + r) * 4096 + col] = acc[i][j][r];
      }
    }
  } else {
    if (n0 >= 4096) {
      u16* C = (u16*)Cv2;
      int cb = n0 - 4096;
#pragma unroll
      for (int i = 0; i < 4; i++) {
        int row = m0 + wm * 64 + i * 16 + lrow * 4;
#pragma unroll
        for (int j = 0; j < 4; j++) {
          int col = cb + wn * 32 + (j & 1) * 16 + (j >> 1) * 64 + lcol;
#pragma unroll
          for (int r = 0; r < 4; r++)
            C[(size_t)(row + r) * 1024 + col] = f2b(acc[i][j][r]);
        }
      }
    } else {
      // In-register Neox RoPE: pair (d, d+64) = (acc[i][j], acc[i][j+2]).
      u16* C = (u16*)Cv;
      float inv[2];
#pragma unroll
      for (int j = 0; j < 2; j++) {
        int d = wn * 32 + j * 16 + lcol;
        inv[j] = exp2f((float)d * (-LOG2_ROPE_BASE / 64.f));
      }
#pragma unroll
      for (int i = 0; i < 4; i++) {
        int row = m0 + wm * 64 + i * 16 + lrow * 4;
#pragma unroll
        for (int r = 0; r < 4; r++) {
          float pos = (float)positions[row + r];
#pragma unroll
          for (int j = 0; j < 2; j++) {
            int d = wn * 32 + j * 16 + lcol;
            float ang = pos * inv[j];
            float sv, cv;
            sincosf(ang, &sv, &cv);
            float x1 = acc[i][j][r];
            float x2 = acc[i][j + 2][r];
            C[(size_t)(row + r) * 4096 + n0 + d] = f2b((x1 * cv - x2 * sv) * QSCALE);
            C[(size_t)(row + r) * 4096 + n0 + d + 64] =
                f2b((x2 * cv + x1 * sv) * QSCALE);
          }
        }
      }
    }
  }
}

// ---------------------------------------------------------------------------
// Flash GQA attention over the compressed cache (bf16 in/out, fp32 acc).
// Block: 4 waves, each owning 32 q-rows; key tile = 64.
// R6 structure:
//   - grid (8, 32): block x handles q-tile PAIR (15-x, x) sequentially ->
//     uniform 34 key-tiles per block, 256 blocks = 1/CU (causal balance).
//   - Q fragments loaded straight from global to registers (no LDS stage).
//   - K/V double-buffered in LDS; 2-phase: STAGE(next) -> compute(cur) ->
//     vmcnt(0)+barrier.  96.5 KB LDS.
//   - T2 XOR swizzle (16B slot ^= (row>>1)&3) on K/V via pre-swizzled GLOBAL
//     source (global_load_lds dest must be linear) + swizzled ds_read; same
//     XOR on Ps write/read.  Kills the 8-way 64B-row bank conflicts.
//   - S^T = K*Q^T; fixed-max exp2 softmax (no running max / rescale).
// ---------------------------------------------------------------------------
__global__ __launch_bounds__(256)
void attn_kernel(const u16* __restrict__ Q, const u16* __restrict__ ckv,
                 const u16* __restrict__ vT, u16* __restrict__ ctx) {
  __shared__ alignas(16) u16 Kt[2][8192];   // 2 x [4 panels][64 keys][32 d] = 32KB
  __shared__ alignas(16) u16 Vt[2][8192];   // 2 x [2 panels][128 d][32 keys] = 32KB
  __shared__ alignas(16) u16 Ps[4][4096];   // per-wave P [2 panels][32 q][32 k] = 32KB
  __shared__ alignas(16) float red[4][32];

  const int tid = threadIdx.x, w = tid >> 6, l = tid & 63;
  const int lrow = l >> 4, lcol = l & 15;
  const int h = blockIdx.y, kh = h >> 3;
  const int q0w = w * 32;
  const int sxor = (l >> 3) & 3;        // staging-side XOR key (row>>1)&3
  const int kxor = (lcol >> 1) & 3;     // read-side XOR key   (row>>1)&3

  // staging: wave covers K rows w*16.. (4 panels) and V rows w*32.. (2 chunks)
  const u16* kg0 = ckv + (size_t)(w * 16 + (l >> 2)) * 1024 + kh * 128 +
                   (((l & 3) ^ sxor)) * 8;
  const u16* vg0 = vT + (size_t)(kh * 128 + w * 32 + (l >> 2)) * 2048 +
                   (((l & 3) ^ sxor)) * 8;

#pragma unroll 1
  for (int qi = 0; qi < 2; qi++) {
    const int qt = qi ? (int)blockIdx.x : 15 - (int)blockIdx.x;

    // Q fragments straight to registers
    s16x8 qf[2][4];
    {
      const u16* qg =
          Q + (size_t)(qt * 128 + q0w + lcol) * 4096 + h * 128 + lrow * 8;
#pragma unroll
      for (int nt = 0; nt < 2; nt++)
#pragma unroll
        for (int kc = 0; kc < 4; kc++)
          qf[nt][kc] = *(const s16x8*)&qg[(size_t)(nt * 16) * 4096 + kc * 32];
    }

    f32x4 o[2][8] = {};
    float l_run[2] = {0.f, 0.f};
    const int nkt = 2 * (qt + 1);

    // prologue: stage key-tile 0 into buffer 0
    {
      const u16* kg = kg0;
#pragma unroll
      for (int kc = 0; kc < 4; kc++)
        async_copy16(&Kt[0][kc * 2048 + (w * 16) * 32], kg + kc * 32);
      const u16* vg = vg0;
#pragma unroll
      for (int kc = 0; kc < 2; kc++) {
        async_copy16(&Vt[0][kc * 4096 + (w * 32) * 32], vg + kc * 32);
        async_copy16(&Vt[0][kc * 4096 + (w * 32 + 16) * 32],
                     vg + (size_t)16 * 2048 + kc * 32);
      }
    }
    asm volatile("s_waitcnt vmcnt(0)" ::: "memory");
    __syncthreads();

#pragma unroll 1
    for (int kt = 0; kt < nkt; kt++) {
      const int cur = kt & 1;
      // issue next tile's stage into the other buffer (lands before the
      // vmcnt(0)+barrier at the end of this iteration)
      if (kt + 1 < nkt) {
        const u16* kg = kg0 + (size_t)(kt + 1) * 64 * 1024;
#pragma unroll
        for (int kc = 0; kc < 4; kc++)
          async_copy16(&Kt[cur ^ 1][kc * 2048 + (w * 16) * 32], kg + kc * 32);
        const u16* vg = vg0 + (size_t)(kt + 1) * 64;
#pragma unroll
        for (int kc = 0; kc < 2; kc++) {
          async_copy16(&Vt[cur ^ 1][kc * 4096 + (w * 32) * 32], vg + kc * 32);
          async_copy16(&Vt[cur ^ 1][kc * 4096 + (w * 32 + 16) * 32],
                       vg + (size_t)16 * 2048 + kc * 32);
        }
      }

      f32x4 s[4][2] = {};
#pragma unroll
      for (int kc = 0; kc < 4; kc++)
#pragma unroll
        for (int mt = 0; mt < 4; mt++) {
          s16x8 ka = *(const s16x8*)&Kt[cur][kc * 2048 + (mt * 16 + lcol) * 32 +
                                            (lrow ^ kxor) * 8];
          s[mt][0] = MFMA16(ka, qf[0][kc], s[mt][0]);
          s[mt][1] = MFMA16(ka, qf[1][kc], s[mt][1]);
        }

      if (kt >= 2 * qt) {  // diagonal 128-block: causal mask
        int koff = (kt & 1) * 64;
#pragma unroll
        for (int mt = 0; mt < 4; mt++)
#pragma unroll
          for (int nt = 0; nt < 2; nt++)
#pragma unroll
            for (int r = 0; r < 4; r++) {
              int key = koff + mt * 16 + lrow * 4 + r;
              int q = q0w + nt * 16 + lcol;
              if (key > q) s[mt][nt][r] = -1e30f;
            }
      }

#pragma unroll
      for (int nt = 0; nt < 2; nt++) {
        float sum = 0.f;
#pragma unroll
        for (int mt = 0; mt < 4; mt++) {
          s16x4 pk;
#pragma unroll
          for (int r = 0; r < 4; r++) {
            float p = exp2f(s[mt][nt][r] - FIXMAX);
            sum += p;
            pk[r] = (short)f2b(p);
          }
          int key = mt * 16 + lrow * 4;
          *(s16x4*)&Ps[w][(key >> 5) * 2048 + (nt * 16 + lcol) * 32 +
                          ((key & 31) ^ (kxor << 3))] = pk;
        }
        sum += __shfl_xor(sum, 16);
        sum += __shfl_xor(sum, 32);
        l_run[nt] += sum;
      }
      // no barrier: Ps[w] is wave-private; HW lgkmcnt orders write->read.

#pragma unroll
      for (int kc = 0; kc < 2; kc++) {
        s16x8 pa0 = *(const s16x8*)&Ps[w][kc * 2048 + lcol * 32 +
                                          (lrow ^ kxor) * 8];
        s16x8 pa1 = *(const s16x8*)&Ps[w][kc * 2048 + (16 + lcol) * 32 +
                                          (lrow ^ kxor) * 8];
#pragma unroll
        for (int ntO = 0; ntO < 8; ntO++) {
          s16x8 vb = *(const s16x8*)&Vt[cur][kc * 4096 + (ntO * 16 + lcol) * 32 +
                                             (lrow ^ kxor) * 8];
          o[0][ntO] = MFMA16(pa0, vb, o[0][ntO]);
          o[1][ntO] = MFMA16(pa1, vb, o[1][ntO]);
        }
      }

      asm volatile("s_waitcnt vmcnt(0)" ::: "memory");
      __syncthreads();
    }

    // epilogue for this q-tile
    if (l < 16) {
      red[w][l] = 1.f / l_run[0];
      red[w][16 + l] = 1.f / l_run[1];
    }
    __syncthreads();
    f32x4 lf0 = *(const f32x4*)&red[w][lrow * 4];
    f32x4 lf1 = *(const f32x4*)&red[w][16 + lrow * 4];
#pragma unroll
    for (int mtO = 0; mtO < 2; mtO++)
#pragma unroll
      for (int ntO = 0; ntO < 8; ntO++)
#pragma unroll
        for (int r = 0; r < 4; r++) {
          float lv = mtO ? lf1[r] : lf0[r];
          int q = qt * 128 + q0w + mtO * 16 + lrow * 4 + r;
          int d = h * 128 + ntO * 16 + lcol;
          ctx[(size_t)q * 4096 + d] = f2b(o[mtO][ntO][r] * lv);
        }
    __syncthreads();  // red[] reused by next qi
  }
}

// ---------------------------------------------------------------------------
extern "C" void kernel_launch(void* const* d_in, const int* in_sizes, int n_in,
                              void* d_out, int out_size, void* d_ws, size_t ws_size,
                              hipStream_t stream) {
  const int* positions = (const int*)d_in[0];
  const float* hidden = (const float*)d_in[1];  // (2048, 4096) fp32
  const float* Wq = (const float*)d_in[2];      // (4096, 4096) fp32
  const float* Wc = (const float*)d_in[3];      // (4096, 1024) fp32
  // d_in[4] (Wuk), d_in[5] (Wuv): dead in the reference -> skipped entirely.
  const float* Wo = (const float*)d_in[6];      // (4096, 4096) fp32

  char* ws = (char*)d_ws;
  u16* hb  = (u16*)(ws);                  // 16,777,216 B : bf16 hidden; later ctx
  u16* WT  = (u16*)(ws + 16777216);       // 41,943,040 B : [WqT;WcT] 5120x4096
  u16* qbf = (u16*)(ws + 58720256);       // 16,777,216 B : rope(q)*scale (bf16)
  u16* ckv = (u16*)(ws + 75497472);       //  4,194,304 B : c_kv bf16
  u16* cvT = (u16*)(ws + 79691776);       //  2,097,152 B : V^T [4][128][2048] bf16
  u16* WoT = (u16*)(ws + 81788928);       // 33,554,432 B : Wo^T bf16
  u16* ctx = hb;                          // reuse: hidden dead after fused GEMM

  dim3 blk(256);

  // one prep launch: hidden convert + Wq/Wc/Wo fp32->bf16 transposes
  prep_kernel<<<dim3(13312), blk, 0, stream>>>(hidden, Wq, Wc, Wo, hb, WT,
                                               WT + (size_t)4096 * 4096, WoT);

  // fused: q = rope(hidden@Wq)*scale -> qbf ; c_kv = hidden@Wc -> ckv
  gemm_bt<1><<<dim3(40, 16), blk, 0, stream>>>(hb, WT, qbf, ckv, positions);

  // V^T per kv head: cvT[kh][d][t] = ckv[t][512 + kh*128 + d]
  transpose_ckv<<<dim3(2, 32, 4), blk, 0, stream>>>(ckv, cvT);

  // flash GQA attention -> ctx (T, 4096) bf16 (overwrites hb; hidden is dead)
  // grid (8, 32): q-tile pairs (15-x, x), uniform work, 1 block/CU
  attn_kernel<<<dim3(8, 32), blk, 0, stream>>>(qbf, ckv, cvT, ctx);

  // out = ctx@Wo -> fp32 d_out, direct store (512 blocks, full K per block)
  gemm_bt<3><<<dim3(32, 16), blk, 0, stream>>>(ctx, WoT, d_out, nullptr,
                                               positions);
}

// Round 3
// 465.656 us; speedup vs baseline: 1.1762x; 1.0368x over previous
//
#include <hip/hip_runtime.h>
#include <hip/hip_bf16.h>
#include <cstdint>
#include <cstddef>

// ---------------------------------------------------------------------------
// CacheShrinkMLAAttention (T=2048, D_MODEL=4096, 32 q-heads, 4 compressed KV
// heads, D_HEAD=128). Live dataflow only:
//   q = rope(hidden@Wq)*scale ; c_kv = hidden@Wc ; flash-GQA over c_k/c_v ;
//   out = ctx@Wo.   (Wuk/Wuv decompression is dead in the reference.)
// Storage: fp32 in/out. Internals: bf16 MFMA, fp32 accumulate.
// R7: attention restructured for 2 blocks/CU (2 waves/SIMD TLP):
//   - block = 4 waves = 4 heads (same kv-group) x one 32-row q-chunk; K/V
//     LDS shared, per-wave work identical -> balanced barriers.
//   - grid 512; qt = (qi<32)?qi:95-qi pairs complementary chunks on the
//     same CU -> uniform 33 key-tiles/CU.  b&7 = head-group -> each XCD
//     sees ONE kv-head (K/V fully L2-local).
//   - LDS 96.5->72KB: single-panel Ps (softmax of panel p interleaved with
//     PV of panel p); 1/l broadcast reuses Ps; red[] gone.
//   - s_setprio(1) around MFMA clusters (2 waves/SIMD -> arbitration pays).
// ---------------------------------------------------------------------------

typedef unsigned short u16;
typedef short s16x8 __attribute__((ext_vector_type(8)));
typedef short s16x4 __attribute__((ext_vector_type(4)));
typedef float f32x4 __attribute__((ext_vector_type(4)));

#define MFMA16(a, b, c) __builtin_amdgcn_mfma_f32_16x16x32_bf16((a), (b), (c), 0, 0, 0)

// 1/sqrt(128) * log2(e): folded into q at rope time; attention uses exp2.
#define QSCALE 0.12751899f
// log2(10000)
#define LOG2_ROPE_BASE 13.287712379549449f
// fixed softmax max (exp2 domain) — exact (no overflow for any plausible score)
#define FIXMAX 24.0f

__device__ __forceinline__ u16 f2b(float f) {
  return __builtin_bit_cast(u16, __float2bfloat16(f));
}
__device__ __forceinline__ void async_copy16(u16* lds, const u16* g) {
  __builtin_amdgcn_global_load_lds(
      (const __attribute__((address_space(1))) unsigned int*)g,
      (__attribute__((address_space(3))) unsigned int*)lds, 16, 0, 0);
}

// ---------------------------------------------------------------------------
// Fused prep: one launch does hidden fp32->bf16 convert + Wq/Wc/Wo
// fp32->bf16 transposes. Linear grid, decoded per job:
//   [0,4096)            : Wq  tp  (64x64 tiles, 64x64 grid)
//   [4096,5120)         : Wc  tp  (16x64 grid)
//   [5120,9216)         : Wo  tp  (64x64 grid)
//   [9216,13312)        : hidden convert (8 elems/thread)
// ---------------------------------------------------------------------------
__global__ __launch_bounds__(256)
void prep_kernel(const float* __restrict__ hidden, const float* __restrict__ Wq,
                 const float* __restrict__ Wc, const float* __restrict__ Wo,
                 u16* __restrict__ hb, u16* __restrict__ WqT,
                 u16* __restrict__ WcT, u16* __restrict__ WoT) {
  __shared__ alignas(16) u16 tile[64 * 72];
  const int b = blockIdx.x;
  const int t = threadIdx.x;

  if (b >= 9216) {  // hidden convert
    int i = (b - 9216) * 256 + t;
    const float4* p = (const float4*)hidden + (size_t)i * 2;
    float4 a = p[0], c = p[1];
    s16x8 v;
    v[0] = (short)f2b(a.x); v[1] = (short)f2b(a.y);
    v[2] = (short)f2b(a.z); v[3] = (short)f2b(a.w);
    v[4] = (short)f2b(c.x); v[5] = (short)f2b(c.y);
    v[6] = (short)f2b(c.z); v[7] = (short)f2b(c.w);
    *(s16x8*)&hb[(size_t)i * 8] = v;
    return;
  }

  const float* in;
  u16* out;
  int gx, in_ld, out_ld;
  if (b < 4096)      { in = Wq; out = WqT; gx = b;        in_ld = 4096; out_ld = 4096; }
  else if (b < 5120) { in = Wc; out = WcT; gx = b - 4096; in_ld = 1024; out_ld = 4096; }
  else               { in = Wo; out = WoT; gx = b - 5120; in_ld = 4096; out_ld = 4096; }
  const int nbx = in_ld / 64;
  const int c0 = (gx % nbx) * 64, r0 = (gx / nbx) * 64;
  const int rr = t >> 3, cc = (t & 7) * 8;
#pragma unroll
  for (int p = 0; p < 2; p++) {
    int row = p * 32 + rr;
    const float4* src = (const float4*)&in[(size_t)(r0 + row) * in_ld + c0 + cc];
    float4 a = src[0], c = src[1];
    s16x8 v;
    v[0] = (short)f2b(a.x); v[1] = (short)f2b(a.y);
    v[2] = (short)f2b(a.z); v[3] = (short)f2b(a.w);
    v[4] = (short)f2b(c.x); v[5] = (short)f2b(c.y);
    v[6] = (short)f2b(c.z); v[7] = (short)f2b(c.w);
    *(s16x8*)&tile[row * 72 + cc] = v;
  }
  __syncthreads();
#pragma unroll
  for (int p = 0; p < 2; p++) {
    int orow = p * 32 + rr;
    s16x8 v;
#pragma unroll
    for (int j = 0; j < 8; j++) v[j] = (short)tile[(cc + j) * 72 + orow];
    *(s16x8*)&out[(size_t)(c0 + orow) * out_ld + r0 + cc] = v;
  }
}

// ---------------------------------------------------------------------------
// bf16 64x64 tile transpose for ckv->V^T, all 4 kv heads in one launch.
// out[kh][c][r] = in[r][512 + kh*128 + c]
// ---------------------------------------------------------------------------
__global__ __launch_bounds__(256)
void transpose_ckv(const u16* __restrict__ in, u16* __restrict__ out) {
  __shared__ alignas(16) u16 tile[64 * 72];
  const int kh = blockIdx.z;
  const int c0 = blockIdx.x * 64, r0 = blockIdx.y * 64;
  const int in_off = 512 + kh * 128;
  u16* outk = out + (size_t)kh * 128 * 2048;
  const int t = threadIdx.x;
  const int rr = t >> 3, cc = (t & 7) * 8;
#pragma unroll
  for (int p = 0; p < 2; p++) {
    int row = p * 32 + rr;
    s16x8 v = *(const s16x8*)&in[(size_t)(r0 + row) * 1024 + in_off + c0 + cc];
    *(s16x8*)&tile[row * 72 + cc] = v;
  }
  __syncthreads();
#pragma unroll
  for (int p = 0; p < 2; p++) {
    int orow = p * 32 + rr;
    s16x8 v;
#pragma unroll
    for (int j = 0; j < 8; j++) v[j] = (short)tile[(cc + j) * 72 + orow];
    *(s16x8*)&outk[(size_t)(c0 + orow) * 2048 + r0 + cc] = v;
  }
}

// ---------------------------------------------------------------------------
// GEMM: C = A(Mx4096,row) * Bt(Nx4096,row)^T, bf16 in, fp32 acc.
// 128x128 block tile, BK=64 staged as TWO 32-wide panels (64B LDS rows ->
// 8-way ds_read conflict, not 16-way), 4 waves (2x2), 4x4 MFMA tiles/wave.
// Column remap: acc tile j covers cols wn*32+(j&1)*16+(j>>1)*64 so RoPE
// pairs (d, d+64) are acc[i][j]/acc[i][j+2] in the SAME lane.
// EPI=1 (fused q/ckv): n0<4096 -> in-register Neox RoPE + QSCALE -> Cv;
//   n0>=4096 -> plain bf16 -> Cv2 (stride 1024).
// EPI=3: plain fp32 store -> Cv (full K per block, no split-K/atomics).
// ---------------------------------------------------------------------------
template <int EPI>
__global__ __launch_bounds__(256, 3)
void gemm_bt(const u16* __restrict__ A, const u16* __restrict__ Bt,
             void* __restrict__ Cv, void* __restrict__ Cv2,
             const int* __restrict__ positions) {
  __shared__ alignas(16) u16 As[2][128 * 32];
  __shared__ alignas(16) u16 Bs[2][128 * 32];

  const int tid = threadIdx.x;
  const int w = tid >> 6, l = tid & 63;
  const int wm = w >> 1, wn = w & 1;
  const int lrow = l >> 4, lcol = l & 15;
  const int m0 = blockIdx.y * 128, n0 = blockIdx.x * 128;

  f32x4 acc[4][4] = {};

  const int srow = l >> 2;            // 0..15 row within a 16-row issue
  const int scol = (l & 3) * 8;       // elem offset within 32-elem row
  const u16* Ag = A + (size_t)(m0 + w * 32 + srow) * 4096 + scol;
  const u16* Bg = Bt + (size_t)(n0 + w * 32 + srow) * 4096 + scol;

  for (int kt = 0; kt < 4096; kt += 64) {
    __syncthreads();
#pragma unroll
    for (int hf = 0; hf < 2; hf++) {
      async_copy16(&As[hf][(w * 32) * 32], Ag + kt + hf * 32);
      async_copy16(&As[hf][(w * 32 + 16) * 32],
                   Ag + (size_t)16 * 4096 + kt + hf * 32);
      async_copy16(&Bs[hf][(w * 32) * 32], Bg + kt + hf * 32);
      async_copy16(&Bs[hf][(w * 32 + 16) * 32],
                   Bg + (size_t)16 * 4096 + kt + hf * 32);
    }
    __syncthreads();

#pragma unroll
    for (int hf = 0; hf < 2; hf++) {
      s16x8 a[4], b[4];
#pragma unroll
      for (int i = 0; i < 4; i++)
        a[i] = *(const s16x8*)&As[hf][(wm * 64 + i * 16 + lcol) * 32 + lrow * 8];
#pragma unroll
      for (int j = 0; j < 4; j++)
        b[j] = *(const s16x8*)&Bs[hf][(wn * 32 + (j & 1) * 16 + (j >> 1) * 64 +
                                       lcol) * 32 + lrow * 8];
#pragma unroll
      for (int i = 0; i < 4; i++)
#pragma unroll
        for (int j = 0; j < 4; j++)
          acc[i][j] = MFMA16(a[i], b[j], acc[i][j]);
    }
  }

  if constexpr (EPI == 3) {
    float* C = (float*)Cv;
#pragma unroll
    for (int i = 0; i < 4; i++) {
      int row = m0 + wm * 64 + i * 16 + lrow * 4;
#pragma unroll
      for (int j = 0; j < 4; j++) {
        int col = n0 + wn * 32 + (j & 1) * 16 + (j >> 1) * 64 + lcol;
#pragma unroll
        for (int r = 0; r < 4; r++)
          C[(size_t)(row + r) * 4096 + col] = acc[i][j][r];
      }
    }
  } else {
    if (n0 >= 4096) {
      u16* C = (u16*)Cv2;
      int cb = n0 - 4096;
#pragma unroll
      for (int i = 0; i < 4; i++) {
        int row = m0 + wm * 64 + i * 16 + lrow * 4;
#pragma unroll
        for (int j = 0; j < 4; j++) {
          int col = cb + wn * 32 + (j & 1) * 16 + (j >> 1) * 64 + lcol;
#pragma unroll
          for (int r = 0; r < 4; r++)
            C[(size_t)(row + r) * 1024 + col] = f2b(acc[i][j][r]);
        }
      }
    } else {
      // In-register Neox RoPE: pair (d, d+64) = (acc[i][j], acc[i][j+2]).
      u16* C = (u16*)Cv;
      float inv[2];
#pragma unroll
      for (int j = 0; j < 2; j++) {
        int d = wn * 32 + j * 16 + lcol;
        inv[j] = exp2f((float)d * (-LOG2_ROPE_BASE / 64.f));
      }
#pragma unroll
      for (int i = 0; i < 4; i++) {
        int row = m0 + wm * 64 + i * 16 + lrow * 4;
#pragma unroll
        for (int r = 0; r < 4; r++) {
          float pos = (float)positions[row + r];
#pragma unroll
          for (int j = 0; j < 2; j++) {
            int d = wn * 32 + j * 16 + lcol;
            float ang = pos * inv[j];
            float sv, cv;
            sincosf(ang, &sv, &cv);
            float x1 = acc[i][j][r];
            float x2 = acc[i][j + 2][r];
            C[(size_t)(row + r) * 4096 + n0 + d] = f2b((x1 * cv - x2 * sv) * QSCALE);
            C[(size_t)(row + r) * 4096 + n0 + d + 64] =
                f2b((x2 * cv + x1 * sv) * QSCALE);
          }
        }
      }
    }
  }
}

// ---------------------------------------------------------------------------
// Flash GQA attention over the compressed cache (bf16 in/out, fp32 acc).
// R7 structure (2 blocks/CU, 2 waves/SIMD):
//   - block = 4 waves; wave w owns head hg*4+w (same kv-group kh=hg>>1) and
//     the block's 32-row q-chunk.  K/V LDS shared; per-wave work identical.
//   - grid 512: b&7 = head-group hg (-> one kv-head per XCD, L2-local K/V);
//     qi=b>>3, qt=(qi<32)?qi:95-qi pairs complementary chunks per CU
//     (uniform 33 key-tiles per CU).
//   - K/V double-buffered (2-phase, vmcnt(0)+barrier per tile); Q in regs.
//   - T2 XOR swizzle (16B slot ^= (row>>1)&3) on K/V via pre-swizzled global
//     source + swizzled ds_read; same XOR on Ps write/read.
//   - single-panel Ps (2KB/wave): softmax(panel p) -> PV(panel p); the
//     write->read->rewrite no-barrier pattern is wave-private + DS in-order.
//   - fixed-max exp2 softmax; 1/l broadcast through Ps scratch at the end.
// LDS: Kt 32KB + Vt 32KB + Ps 8KB = 72KB -> 2 blocks/CU.
// ---------------------------------------------------------------------------
__global__ __launch_bounds__(256, 2)
void attn_kernel(const u16* __restrict__ Q, const u16* __restrict__ ckv,
                 const u16* __restrict__ vT, u16* __restrict__ ctx) {
  __shared__ alignas(16) u16 Kt[2][8192];   // 2 x [4 panels][64 keys][32 d] = 32KB
  __shared__ alignas(16) u16 Vt[2][8192];   // 2 x [2 panels][128 d][32 keys] = 32KB
  __shared__ alignas(16) u16 Ps[4][1024];   // per-wave P [32 q][32 k] = 8KB

  const int tid = threadIdx.x, w = tid >> 6, l = tid & 63;
  const int lrow = l >> 4, lcol = l & 15;
  const int b = blockIdx.x;
  const int hg = b & 7;                  // head-group: heads hg*4..hg*4+3
  const int qi = b >> 3;                 // 0..63
  const int qt = (qi < 32) ? qi : 95 - qi;  // complementary CU pairing
  const int kh = hg >> 1;
  const int h = hg * 4 + w;              // this wave's head
  const int nkt = (qt >> 1) + 1;         // causal key-tile count
  const int sxor = (l >> 3) & 3;         // staging-side XOR key (row>>1)&3
  const int kxor = (lcol >> 1) & 3;      // read-side XOR key   (row>>1)&3

  // staging: wave covers K keys w*16.. (4 d-panels) and V d-rows w*32..
  const u16* kg0 = ckv + (size_t)(w * 16 + (l >> 2)) * 1024 + kh * 128 +
                   ((l & 3) ^ sxor) * 8;
  const u16* vg0 = vT + (size_t)(kh * 128 + w * 32 + (l >> 2)) * 2048 +
                   ((l & 3) ^ sxor) * 8;

  // Q fragments straight to registers (rows qt*32 + nt*16 + lcol)
  s16x8 qf[2][4];
  {
    const u16* qg = Q + (size_t)(qt * 32 + lcol) * 4096 + h * 128 + lrow * 8;
#pragma unroll
    for (int nt = 0; nt < 2; nt++)
#pragma unroll
      for (int kc = 0; kc < 4; kc++)
        qf[nt][kc] = *(const s16x8*)&qg[(size_t)(nt * 16) * 4096 + kc * 32];
  }

  f32x4 o[2][8] = {};
  float l_run[2] = {0.f, 0.f};

  // prologue: stage key-tile 0 into buffer 0
  {
#pragma unroll
    for (int kc = 0; kc < 4; kc++)
      async_copy16(&Kt[0][kc * 2048 + (w * 16) * 32], kg0 + kc * 32);
#pragma unroll
    for (int kc = 0; kc < 2; kc++) {
      async_copy16(&Vt[0][kc * 4096 + (w * 32) * 32], vg0 + kc * 32);
      async_copy16(&Vt[0][kc * 4096 + (w * 32 + 16) * 32],
                   vg0 + (size_t)16 * 2048 + kc * 32);
    }
  }
  asm volatile("s_waitcnt vmcnt(0)" ::: "memory");
  __syncthreads();

#pragma unroll 1
  for (int kt = 0; kt < nkt; kt++) {
    const int cur = kt & 1;
    // issue next tile's stage into the other buffer
    if (kt + 1 < nkt) {
      const u16* kg = kg0 + (size_t)(kt + 1) * 64 * 1024;
#pragma unroll
      for (int kc = 0; kc < 4; kc++)
        async_copy16(&Kt[cur ^ 1][kc * 2048 + (w * 16) * 32], kg + kc * 32);
      const u16* vg = vg0 + (size_t)(kt + 1) * 64;
#pragma unroll
      for (int kc = 0; kc < 2; kc++) {
        async_copy16(&Vt[cur ^ 1][kc * 4096 + (w * 32) * 32], vg + kc * 32);
        async_copy16(&Vt[cur ^ 1][kc * 4096 + (w * 32 + 16) * 32],
                     vg + (size_t)16 * 2048 + kc * 32);
      }
    }

    f32x4 s[4][2] = {};
    __builtin_amdgcn_s_setprio(1);
#pragma unroll
    for (int kc = 0; kc < 4; kc++)
#pragma unroll
      for (int mt = 0; mt < 4; mt++) {
        s16x8 ka = *(const s16x8*)&Kt[cur][kc * 2048 + (mt * 16 + lcol) * 32 +
                                          (lrow ^ kxor) * 8];
        s[mt][0] = MFMA16(ka, qf[0][kc], s[mt][0]);
        s[mt][1] = MFMA16(ka, qf[1][kc], s[mt][1]);
      }
    __builtin_amdgcn_s_setprio(0);

    if (kt == nkt - 1) {  // final (diagonal) tile: causal mask
      const int qoff = (qt & 1) * 32;
#pragma unroll
      for (int mt = 0; mt < 4; mt++)
#pragma unroll
        for (int nt = 0; nt < 2; nt++)
#pragma unroll
          for (int r = 0; r < 4; r++) {
            int key = mt * 16 + lrow * 4 + r;
            int q = qoff + nt * 16 + lcol;
            if (key > q) s[mt][nt][r] = -1e30f;
          }
    }

    // softmax(panel) -> PV(panel), single Ps panel per wave
#pragma unroll
    for (int pan = 0; pan < 2; pan++) {
#pragma unroll
      for (int nt = 0; nt < 2; nt++)
#pragma unroll
        for (int mi = 0; mi < 2; mi++) {
          const int mt = pan * 2 + mi;
          s16x4 pk;
#pragma unroll
          for (int r = 0; r < 4; r++) {
            float p = exp2f(s[mt][nt][r] - FIXMAX);
            l_run[nt] += p;
            pk[r] = (short)f2b(p);
          }
          const int key32 = mi * 16 + lrow * 4;
          *(s16x4*)&Ps[w][(nt * 16 + lcol) * 32 + (key32 ^ (kxor << 3))] = pk;
        }
      // no barrier: Ps[w] is wave-private; DS pipe is in-order per wave.
      s16x8 pa0 = *(const s16x8*)&Ps[w][lcol * 32 + (lrow ^ kxor) * 8];
      s16x8 pa1 = *(const s16x8*)&Ps[w][(16 + lcol) * 32 + (lrow ^ kxor) * 8];
      __builtin_amdgcn_s_setprio(1);
#pragma unroll
      for (int ntO = 0; ntO < 8; ntO++) {
        s16x8 vb = *(const s16x8*)&Vt[cur][pan * 4096 + (ntO * 16 + lcol) * 32 +
                                           (lrow ^ kxor) * 8];
        o[0][ntO] = MFMA16(pa0, vb, o[0][ntO]);
        o[1][ntO] = MFMA16(pa1, vb, o[1][ntO]);
      }
      __builtin_amdgcn_s_setprio(0);
    }

    asm volatile("s_waitcnt vmcnt(0)" ::: "memory");
    __syncthreads();
  }

  // reduce l_run across the 4 lrow replicas (lanes l, l^16, l^32, l^48)
#pragma unroll
  for (int nt = 0; nt < 2; nt++) {
    l_run[nt] += __shfl_xor(l_run[nt], 16);
    l_run[nt] += __shfl_xor(l_run[nt], 32);
  }
  // broadcast 1/l via wave-private Ps scratch (kt loop done; Ps free)
  float* fl = (float*)&Ps[w][0];
  if (l < 16) {
    fl[l] = 1.f / l_run[0];
    fl[16 + l] = 1.f / l_run[1];
  }
  f32x4 lf0 = *(const f32x4*)&fl[lrow * 4];
  f32x4 lf1 = *(const f32x4*)&fl[16 + lrow * 4];
#pragma unroll
  for (int mtO = 0; mtO < 2; mtO++)
#pragma unroll
    for (int ntO = 0; ntO < 8; ntO++)
#pragma unroll
      for (int r = 0; r < 4; r++) {
        float lv = mtO ? lf1[r] : lf0[r];
        int q = qt * 32 + mtO * 16 + lrow * 4 + r;
        int d = h * 128 + ntO * 16 + lcol;
        ctx[(size_t)q * 4096 + d] = f2b(o[mtO][ntO][r] * lv);
      }
}

// ---------------------------------------------------------------------------
extern "C" void kernel_launch(void* const* d_in, const int* in_sizes, int n_in,
                              void* d_out, int out_size, void* d_ws, size_t ws_size,
                              hipStream_t stream) {
  const int* positions = (const int*)d_in[0];
  const float* hidden = (const float*)d_in[1];  // (2048, 4096) fp32
  const float* Wq = (const float*)d_in[2];      // (4096, 4096) fp32
  const float* Wc = (const float*)d_in[3];      // (4096, 1024) fp32
  // d_in[4] (Wuk), d_in[5] (Wuv): dead in the reference -> skipped entirely.
  const float* Wo = (const float*)d_in[6];      // (4096, 4096) fp32

  char* ws = (char*)d_ws;
  u16* hb  = (u16*)(ws);                  // 16,777,216 B : bf16 hidden; later ctx
  u16* WT  = (u16*)(ws + 16777216);       // 41,943,040 B : [WqT;WcT] 5120x4096
  u16* qbf = (u16*)(ws + 58720256);       // 16,777,216 B : rope(q)*scale (bf16)
  u16* ckv = (u16*)(ws + 75497472);       //  4,194,304 B : c_kv bf16
  u16* cvT = (u16*)(ws + 79691776);       //  2,097,152 B : V^T [4][128][2048] bf16
  u16* WoT = (u16*)(ws + 81788928);       // 33,554,432 B : Wo^T bf16
  u16* ctx = hb;                          // reuse: hidden dead after fused GEMM

  dim3 blk(256);

  // one prep launch: hidden convert + Wq/Wc/Wo fp32->bf16 transposes
  prep_kernel<<<dim3(13312), blk, 0, stream>>>(hidden, Wq, Wc, Wo, hb, WT,
                                               WT + (size_t)4096 * 4096, WoT);

  // fused: q = rope(hidden@Wq)*scale -> qbf ; c_kv = hidden@Wc -> ckv
  gemm_bt<1><<<dim3(40, 16), blk, 0, stream>>>(hb, WT, qbf, ckv, positions);

  // V^T per kv head: cvT[kh][d][t] = ckv[t][512 + kh*128 + d]
  transpose_ckv<<<dim3(2, 32, 4), blk, 0, stream>>>(ckv, cvT);

  // flash GQA attention -> ctx (T, 4096) bf16 (overwrites hb; hidden is dead)
  // grid 512: 64 q-chunks x 8 head-groups, 2 blocks/CU
  attn_kernel<<<dim3(512), blk, 0, stream>>>(qbf, ckv, cvT, ctx);

  // out = ctx@Wo -> fp32 d_out, direct store (512 blocks, full K per block)
  gemm_bt<3><<<dim3(32, 16), blk, 0, stream>>>(ctx, WoT, d_out, nullptr,
                                               positions);
}

// Round 6
// 458.337 us; speedup vs baseline: 1.1950x; 1.0160x over previous
//
#include <hip/hip_runtime.h>
#include <hip/hip_bf16.h>
#include <cstdint>
#include <cstddef>

// ---------------------------------------------------------------------------
// CacheShrinkMLAAttention (T=2048, D_MODEL=4096, 32 q-heads, 4 compressed KV
// heads, D_HEAD=128). Live dataflow only:
//   q = rope(hidden@Wq)*scale ; c_kv = hidden@Wc ; flash-GQA over c_k/c_v ;
//   out = ctx@Wo.   (Wuk/Wuv decompression is dead in the reference.)
// Storage: fp32 in/out. Internals: bf16 MFMA, fp32 accumulate.
// R8 (3rd submit — two container-level infra failures; kernel never ran.
// Audit x2 found no deadlock/OOB path; all barriers wave-uniform, loops
// finite, remaps bijective, swizzles verified involutions):
//  - attn: KVBLK 64->32, 16 q-rows/wave, grid 1024, LDS 36KB -> 4 blocks/CU
//    (4 waves/SIMD TLP; R7 was occupancy-capped at 2 by 72KB LDS).
//    Co-resident qi {i,i+32,i+64,i+96} -> qt map [i,63-i,64+i,127-i] keeps
//    per-CU causal work uniform (~131 key-tiles/CU).
//  - gemm: T1 XCD chunking (each XCD gets an n-column chunk) + T2 both-sides
//    swizzle (stage source col ^((l>>3)&3), read slot ^((lcol>>1)&3)):
//    8-way ds_read conflicts -> 2-way (free).
// ---------------------------------------------------------------------------

typedef unsigned short u16;
typedef short s16x8 __attribute__((ext_vector_type(8)));
typedef short s16x4 __attribute__((ext_vector_type(4)));
typedef float f32x4 __attribute__((ext_vector_type(4)));

#define MFMA16(a, b, c) __builtin_amdgcn_mfma_f32_16x16x32_bf16((a), (b), (c), 0, 0, 0)

// 1/sqrt(128) * log2(e): folded into q at rope time; attention uses exp2.
#define QSCALE 0.12751899f
// log2(10000)
#define LOG2_ROPE_BASE 13.287712379549449f
// fixed softmax max (exp2 domain) — exact (no overflow for any plausible score)
#define FIXMAX 24.0f

__device__ __forceinline__ u16 f2b(float f) {
  return __builtin_bit_cast(u16, __float2bfloat16(f));
}
__device__ __forceinline__ void async_copy16(u16* lds, const u16* g) {
  __builtin_amdgcn_global_load_lds(
      (const __attribute__((address_space(1))) unsigned int*)g,
      (__attribute__((address_space(3))) unsigned int*)lds, 16, 0, 0);
}

// ---------------------------------------------------------------------------
// Fused prep: one launch does hidden fp32->bf16 convert + Wq/Wc/Wo
// fp32->bf16 transposes. Linear grid, decoded per job:
//   [0,4096)            : Wq  tp  (64x64 tiles, 64x64 grid)
//   [4096,5120)         : Wc  tp  (16x64 grid)
//   [5120,9216)         : Wo  tp  (64x64 grid)
//   [9216,13312)        : hidden convert (8 elems/thread)
// ---------------------------------------------------------------------------
__global__ __launch_bounds__(256)
void prep_kernel(const float* __restrict__ hidden, const float* __restrict__ Wq,
                 const float* __restrict__ Wc, const float* __restrict__ Wo,
                 u16* __restrict__ hb, u16* __restrict__ WqT,
                 u16* __restrict__ WcT, u16* __restrict__ WoT) {
  __shared__ alignas(16) u16 tile[64 * 72];
  const int b = blockIdx.x;
  const int t = threadIdx.x;

  if (b >= 9216) {  // hidden convert
    int i = (b - 9216) * 256 + t;
    const float4* p = (const float4*)hidden + (size_t)i * 2;
    float4 a = p[0], c = p[1];
    s16x8 v;
    v[0] = (short)f2b(a.x); v[1] = (short)f2b(a.y);
    v[2] = (short)f2b(a.z); v[3] = (short)f2b(a.w);
    v[4] = (short)f2b(c.x); v[5] = (short)f2b(c.y);
    v[6] = (short)f2b(c.z); v[7] = (short)f2b(c.w);
    *(s16x8*)&hb[(size_t)i * 8] = v;
    return;
  }

  const float* in;
  u16* out;
  int gx, in_ld, out_ld;
  if (b < 4096)      { in = Wq; out = WqT; gx = b;        in_ld = 4096; out_ld = 4096; }
  else if (b < 5120) { in = Wc; out = WcT; gx = b - 4096; in_ld = 1024; out_ld = 4096; }
  else               { in = Wo; out = WoT; gx = b - 5120; in_ld = 4096; out_ld = 4096; }
  const int nbx = in_ld / 64;
  const int c0 = (gx % nbx) * 64, r0 = (gx / nbx) * 64;
  const int rr = t >> 3, cc = (t & 7) * 8;
#pragma unroll
  for (int p = 0; p < 2; p++) {
    int row = p * 32 + rr;
    const float4* src = (const float4*)&in[(size_t)(r0 + row) * in_ld + c0 + cc];
    float4 a = src[0], c = src[1];
    s16x8 v;
    v[0] = (short)f2b(a.x); v[1] = (short)f2b(a.y);
    v[2] = (short)f2b(a.z); v[3] = (short)f2b(a.w);
    v[4] = (short)f2b(c.x); v[5] = (short)f2b(c.y);
    v[6] = (short)f2b(c.z); v[7] = (short)f2b(c.w);
    *(s16x8*)&tile[row * 72 + cc] = v;
  }
  __syncthreads();
#pragma unroll
  for (int p = 0; p < 2; p++) {
    int orow = p * 32 + rr;
    s16x8 v;
#pragma unroll
    for (int j = 0; j < 8; j++) v[j] = (short)tile[(cc + j) * 72 + orow];
    *(s16x8*)&out[(size_t)(c0 + orow) * out_ld + r0 + cc] = v;
  }
}

// ---------------------------------------------------------------------------
// bf16 64x64 tile transpose for ckv->V^T, all 4 kv heads in one launch.
// out[kh][c][r] = in[r][512 + kh*128 + c]
// ---------------------------------------------------------------------------
__global__ __launch_bounds__(256)
void transpose_ckv(const u16* __restrict__ in, u16* __restrict__ out) {
  __shared__ alignas(16) u16 tile[64 * 72];
  const int kh = blockIdx.z;
  const int c0 = blockIdx.x * 64, r0 = blockIdx.y * 64;
  const int in_off = 512 + kh * 128;
  u16* outk = out + (size_t)kh * 128 * 2048;
  const int t = threadIdx.x;
  const int rr = t >> 3, cc = (t & 7) * 8;
#pragma unroll
  for (int p = 0; p < 2; p++) {
    int row = p * 32 + rr;
    s16x8 v = *(const s16x8*)&in[(size_t)(r0 + row) * 1024 + in_off + c0 + cc];
    *(s16x8*)&tile[row * 72 + cc] = v;
  }
  __syncthreads();
#pragma unroll
  for (int p = 0; p < 2; p++) {
    int orow = p * 32 + rr;
    s16x8 v;
#pragma unroll
    for (int j = 0; j < 8; j++) v[j] = (short)tile[(cc + j) * 72 + orow];
    *(s16x8*)&outk[(size_t)(c0 + orow) * 2048 + r0 + cc] = v;
  }
}

// ---------------------------------------------------------------------------
// GEMM: C = A(Mx4096,row) * Bt(Nx4096,row)^T, bf16 in, fp32 acc.
// 128x128 block tile, BK=64 as two 32-wide LDS panels, 4 waves (2x2),
// 4x4 MFMA tiles per wave.
// R8: T1 XCD chunking (XCD k owns an n-column chunk of the grid) and T2
// both-sides swizzle: stage source col ^((l>>3)&3) (global side; LDS dest
// stays linear for global_load_lds), read slot ^((lcol>>1)&3).
// Column remap: acc tile j covers cols wn*32+(j&1)*16+(j>>1)*64 so RoPE
// pairs (d, d+64) are acc[i][j]/acc[i][j+2] in the SAME lane.
// EPI=1 (fused q/ckv): n0<4096 -> in-register Neox RoPE + QSCALE -> Cv;
//   n0>=4096 -> plain bf16 -> Cv2 (stride 1024).
// EPI=3: plain fp32 store -> Cv (full K per block, no split-K/atomics).
// ---------------------------------------------------------------------------
template <int EPI>
__global__ __launch_bounds__(256, 3)
void gemm_bt(const u16* __restrict__ A, const u16* __restrict__ Bt,
             void* __restrict__ Cv, void* __restrict__ Cv2,
             const int* __restrict__ positions) {
  __shared__ alignas(16) u16 As[2][128 * 32];
  __shared__ alignas(16) u16 Bs[2][128 * 32];

  const int tid = threadIdx.x;
  const int w = tid >> 6, l = tid & 63;
  const int wm = w >> 1, wn = w & 1;
  const int lrow = l >> 4, lcol = l & 15;

  // T1: XCD k (= hwid%8 under round-robin dispatch) owns n-columns
  // [cpx*k, cpx*k+cpx) across all m-rows.
  const int wgid = (int)blockIdx.y * (int)gridDim.x + (int)blockIdx.x;
  const int cpx = (int)gridDim.x >> 3;
  const int xk = wgid & 7, xr = wgid >> 3;
  const int bx = cpx * xk + xr % cpx, by = xr / cpx;
  const int m0 = by * 128, n0 = bx * 128;

  f32x4 acc[4][4] = {};

  const int srow = l >> 2;                       // LDS row within a 16-row issue
  const int scol = ((l & 3) ^ ((l >> 3) & 3)) * 8;  // T2 pre-swizzled source col
  const int rxor = (lcol >> 1) & 3;              // T2 read-side XOR key
  const u16* Ag = A + (size_t)(m0 + w * 32 + srow) * 4096 + scol;
  const u16* Bg = Bt + (size_t)(n0 + w * 32 + srow) * 4096 + scol;

  for (int kt = 0; kt < 4096; kt += 64) {
    __syncthreads();
#pragma unroll
    for (int hf = 0; hf < 2; hf++) {
      async_copy16(&As[hf][(w * 32) * 32], Ag + kt + hf * 32);
      async_copy16(&As[hf][(w * 32 + 16) * 32],
                   Ag + (size_t)16 * 4096 + kt + hf * 32);
      async_copy16(&Bs[hf][(w * 32) * 32], Bg + kt + hf * 32);
      async_copy16(&Bs[hf][(w * 32 + 16) * 32],
                   Bg + (size_t)16 * 4096 + kt + hf * 32);
    }
    __syncthreads();

#pragma unroll
    for (int hf = 0; hf < 2; hf++) {
      s16x8 a[4], b[4];
#pragma unroll
      for (int i = 0; i < 4; i++)
        a[i] = *(const s16x8*)&As[hf][(wm * 64 + i * 16 + lcol) * 32 +
                                      (lrow ^ rxor) * 8];
#pragma unroll
      for (int j = 0; j < 4; j++)
        b[j] = *(const s16x8*)&Bs[hf][(wn * 32 + (j & 1) * 16 + (j >> 1) * 64 +
                                       lcol) * 32 + (lrow ^ rxor) * 8];
#pragma unroll
      for (int i = 0; i < 4; i++)
#pragma unroll
        for (int j = 0; j < 4; j++)
          acc[i][j] = MFMA16(a[i], b[j], acc[i][j]);
    }
  }

  if constexpr (EPI == 3) {
    float* C = (float*)Cv;
#pragma unroll
    for (int i = 0; i < 4; i++) {
      int row = m0 + wm * 64 + i * 16 + lrow * 4;
#pragma unroll
      for (int j = 0; j < 4; j++) {
        int col = n0 + wn * 32 + (j & 1) * 16 + (j >> 1) * 64 + lcol;
#pragma unroll
        for (int r = 0; r < 4; r++)
          C[(size_t)(row + r) * 4096 + col] = acc[i][j][r];
      }
    }
  } else {
    if (n0 >= 4096) {
      u16* C = (u16*)Cv2;
      int cb = n0 - 4096;
#pragma unroll
      for (int i = 0; i < 4; i++) {
        int row = m0 + wm * 64 + i * 16 + lrow * 4;
#pragma unroll
        for (int j = 0; j < 4; j++) {
          int col = cb + wn * 32 + (j & 1) * 16 + (j >> 1) * 64 + lcol;
#pragma unroll
          for (int r = 0; r < 4; r++)
            C[(size_t)(row + r) * 1024 + col] = f2b(acc[i][j][r]);
        }
      }
    } else {
      // In-register Neox RoPE: pair (d, d+64) = (acc[i][j], acc[i][j+2]).
      u16* C = (u16*)Cv;
      float inv[2];
#pragma unroll
      for (int j = 0; j < 2; j++) {
        int d = wn * 32 + j * 16 + lcol;
        inv[j] = exp2f((float)d * (-LOG2_ROPE_BASE / 64.f));
      }
#pragma unroll
      for (int i = 0; i < 4; i++) {
        int row = m0 + wm * 64 + i * 16 + lrow * 4;
#pragma unroll
        for (int r = 0; r < 4; r++) {
          float pos = (float)positions[row + r];
#pragma unroll
          for (int j = 0; j < 2; j++) {
            int d = wn * 32 + j * 16 + lcol;
            float ang = pos * inv[j];
            float sv, cv;
            sincosf(ang, &sv, &cv);
            float x1 = acc[i][j][r];
            float x2 = acc[i][j + 2][r];
            C[(size_t)(row + r) * 4096 + n0 + d] = f2b((x1 * cv - x2 * sv) * QSCALE);
            C[(size_t)(row + r) * 4096 + n0 + d + 64] =
                f2b((x2 * cv + x1 * sv) * QSCALE);
          }
        }
      }
    }
  }
}

// ---------------------------------------------------------------------------
// Flash GQA attention over the compressed cache (bf16 in/out, fp32 acc).
// R8 structure (4 blocks/CU, 4 waves/SIMD):
//   - block = 4 waves; wave w owns head hg*4+w (kv-group kh=hg>>1) and the
//     block's 16-row q-chunk.  KVBLK=32.  K/V LDS shared by the 4 waves.
//   - grid 1024: b&7 = head-group hg (one kv-head per XCD -> L2-local K/V);
//     qi=b>>3 (0..127); co-resident qi {i,i+32,i+64,i+96} map to
//     qt = [i, 63-i, 64+i, 127-i] -> uniform causal work per CU.
//   - K/V double-buffered (2-phase: issue next stage, compute cur,
//     vmcnt(0)+barrier).  Q fragments in registers.
//   - T2 XOR swizzle (16B slot ^= (row>>1)&3) on K/V via pre-swizzled global
//     source + swizzled ds_read; same XOR on Ps write/read.
//   - single-panel wave-private Ps (1KB/wave); fixed-max exp2 softmax;
//     1/l broadcast through Ps scratch (DS ops are wave-order -> no barrier).
// LDS: Kt 16KB + Vt 16KB + Ps 4KB = 36KB -> 4 blocks/CU.
// ---------------------------------------------------------------------------
__global__ __launch_bounds__(256, 4)
void attn_kernel(const u16* __restrict__ Q, const u16* __restrict__ ckv,
                 const u16* __restrict__ vT, u16* __restrict__ ctx) {
  __shared__ alignas(16) u16 Kt[2][4096];  // [4 kc][32 keys][32 d] per buf, 16KB
  __shared__ alignas(16) u16 Vt[2][4096];  // [128 d][32 keys] per buf, 16KB
  __shared__ alignas(16) u16 Ps[4][512];   // per-wave P [16 q][32 k], 4KB

  const int tid = threadIdx.x, w = tid >> 6, l = tid & 63;
  const int lrow = l >> 4, lcol = l & 15;
  const int b = blockIdx.x;
  const int hg = b & 7;                 // head-group: heads hg*4..hg*4+3
  const int qi = b >> 3;                // 0..127
  const int ji = qi >> 5, ii = qi & 31;
  const int qt = (ji == 0) ? ii : (ji == 1) ? 63 - ii
               : (ji == 2) ? 64 + ii : 127 - ii;   // 16-row q-chunk, 0..127
  const int kh = hg >> 1;
  const int h = hg * 4 + w;             // this wave's head
  const int nkt = (qt >> 1) + 1;        // causal 32-key tile count
  const int sxor = (l >> 3) & 3;        // staging-side XOR key ((row>>1)&3)
  const int kxor = (lcol >> 1) & 3;     // read-side XOR key

  // staging pointers (T2 pre-swizzled global source; LDS dest linear):
  // K: wave w stages d-panel kc=w: LDS Kt[w*1024 + key*32 + slot*8] <-
  //    ckv[kt*32+key][kh*128 + w*32 + (slot^sxor)*8], key = l>>2 (+16)
  const u16* kg0 = ckv + (size_t)(l >> 2) * 1024 + kh * 128 + w * 32 +
                   ((l & 3) ^ sxor) * 8;
  // V: wave w stages d-rows w*32..+31: LDS Vt[d*32 + slot*8] <-
  //    vT[kh*128+d][kt*32 + (slot^sxor)*8], d = w*32 + (l>>2) (+16)
  const u16* vg0 = vT + (size_t)(kh * 128 + w * 32 + (l >> 2)) * 2048 +
                   ((l & 3) ^ sxor) * 8;

  // Q fragments straight to registers (q-rows qt*16 + lcol)
  s16x8 qf[4];
  {
    const u16* qg = Q + (size_t)(qt * 16 + lcol) * 4096 + h * 128 + lrow * 8;
#pragma unroll
    for (int kc = 0; kc < 4; kc++)
      qf[kc] = *(const s16x8*)&qg[kc * 32];
  }

  f32x4 o[8] = {};
  float lsum = 0.f;

  // prologue: stage key-tile 0 into buffer 0 (4 issues/thread)
  {
    async_copy16(&Kt[0][w * 1024], kg0);
    async_copy16(&Kt[0][w * 1024 + 512], kg0 + (size_t)16 * 1024);
    async_copy16(&Vt[0][w * 1024], vg0);
    async_copy16(&Vt[0][w * 1024 + 512], vg0 + (size_t)16 * 2048);
  }
  asm volatile("s_waitcnt vmcnt(0)" ::: "memory");
  __syncthreads();

#pragma unroll 1
  for (int kt = 0; kt < nkt; kt++) {
    const int cur = kt & 1;
    // issue next tile's stage into the other buffer
    if (kt + 1 < nkt) {
      const u16* kg = kg0 + (size_t)(kt + 1) * 32 * 1024;
      const u16* vg = vg0 + (size_t)(kt + 1) * 32;
      async_copy16(&Kt[cur ^ 1][w * 1024], kg);
      async_copy16(&Kt[cur ^ 1][w * 1024 + 512], kg + (size_t)16 * 1024);
      async_copy16(&Vt[cur ^ 1][w * 1024], vg);
      async_copy16(&Vt[cur ^ 1][w * 1024 + 512], vg + (size_t)16 * 2048);
    }

    // S^T = K * Q^T : s[mt] rows = keys mt*16+lrow*4+r, col = q lcol
    f32x4 s[2] = {};
    __builtin_amdgcn_s_setprio(1);
#pragma unroll
    for (int kc = 0; kc < 4; kc++) {
#pragma unroll
      for (int mt = 0; mt < 2; mt++) {
        s16x8 ka = *(const s16x8*)&Kt[cur][kc * 1024 + (mt * 16 + lcol) * 32 +
                                          (lrow ^ kxor) * 8];
        s[mt] = MFMA16(ka, qf[kc], s[mt]);
      }
    }
    __builtin_amdgcn_s_setprio(0);

    if (kt == nkt - 1) {  // diagonal tile: causal mask
      const int qloc = (qt & 1) * 16 + lcol;
#pragma unroll
      for (int mt = 0; mt < 2; mt++)
#pragma unroll
        for (int r = 0; r < 4; r++) {
          int key = mt * 16 + lrow * 4 + r;
          if (key > qloc) s[mt][r] = -1e30f;
        }
    }

    // softmax -> Ps (wave-private, swizzled write)
#pragma unroll
    for (int mt = 0; mt < 2; mt++) {
      s16x4 pk;
#pragma unroll
      for (int r = 0; r < 4; r++) {
        float p = exp2f(s[mt][r] - FIXMAX);
        lsum += p;
        pk[r] = (short)f2b(p);
      }
      const int key32 = mt * 16 + lrow * 4;
      *(s16x4*)&Ps[w][lcol * 32 + (key32 ^ (kxor << 3))] = pk;
    }
    // no barrier: Ps[w] is wave-private; DS pipe is in-order per wave.

    // PV: o[ntO] += P * V
    s16x8 pa = *(const s16x8*)&Ps[w][lcol * 32 + (lrow ^ kxor) * 8];
    __builtin_amdgcn_s_setprio(1);
#pragma unroll
    for (int ntO = 0; ntO < 8; ntO++) {
      s16x8 vb = *(const s16x8*)&Vt[cur][(ntO * 16 + lcol) * 32 +
                                         (lrow ^ kxor) * 8];
      o[ntO] = MFMA16(pa, vb, o[ntO]);
    }
    __builtin_amdgcn_s_setprio(0);

    asm volatile("s_waitcnt vmcnt(0)" ::: "memory");
    __syncthreads();
  }

  // reduce lsum across the 4 lrow replicas (q = lcol is the live index)
  lsum += __shfl_xor(lsum, 16);
  lsum += __shfl_xor(lsum, 32);
  // broadcast 1/l via wave-private Ps scratch (kt loop done; Ps free)
  float* fl = (float*)&Ps[w][0];
  if (l < 16) fl[l] = 1.f / lsum;
  f32x4 lf = *(const f32x4*)&fl[lrow * 4];
#pragma unroll
  for (int ntO = 0; ntO < 8; ntO++)
#pragma unroll
    for (int r = 0; r < 4; r++) {
      int q = qt * 16 + lrow * 4 + r;
      int d = h * 128 + ntO * 16 + lcol;
      ctx[(size_t)q * 4096 + d] = f2b(o[ntO][r] * lf[r]);
    }
}

// ---------------------------------------------------------------------------
extern "C" void kernel_launch(void* const* d_in, const int* in_sizes, int n_in,
                              void* d_out, int out_size, void* d_ws, size_t ws_size,
                              hipStream_t stream) {
  const int* positions = (const int*)d_in[0];
  const float* hidden = (const float*)d_in[1];  // (2048, 4096) fp32
  const float* Wq = (const float*)d_in[2];      // (4096, 4096) fp32
  const float* Wc = (const float*)d_in[3];      // (4096, 1024) fp32
  // d_in[4] (Wuk), d_in[5] (Wuv): dead in the reference -> skipped entirely.
  const float* Wo = (const float*)d_in[6];      // (4096, 4096) fp32

  char* ws = (char*)d_ws;
  u16* hb  = (u16*)(ws);                  // 16,777,216 B : bf16 hidden; later ctx
  u16* WT  = (u16*)(ws + 16777216);       // 41,943,040 B : [WqT;WcT] 5120x4096
  u16* qbf = (u16*)(ws + 58720256);       // 16,777,216 B : rope(q)*scale (bf16)
  u16* ckv = (u16*)(ws + 75497472);       //  4,194,304 B : c_kv bf16
  u16* cvT = (u16*)(ws + 79691776);       //  2,097,152 B : V^T [4][128][2048] bf16
  u16* WoT = (u16*)(ws + 81788928);       // 33,554,432 B : Wo^T bf16
  u16* ctx = hb;                          // reuse: hidden dead after fused GEMM

  dim3 blk(256);

  // one prep launch: hidden convert + Wq/Wc/Wo fp32->bf16 transposes
  prep_kernel<<<dim3(13312), blk, 0, stream>>>(hidden, Wq, Wc, Wo, hb, WT,
                                               WT + (size_t)4096 * 4096, WoT);

  // fused: q = rope(hidden@Wq)*scale -> qbf ; c_kv = hidden@Wc -> ckv
  gemm_bt<1><<<dim3(40, 16), blk, 0, stream>>>(hb, WT, qbf, ckv, positions);

  // V^T per kv head: cvT[kh][d][t] = ckv[t][512 + kh*128 + d]
  transpose_ckv<<<dim3(2, 32, 4), blk, 0, stream>>>(ckv, cvT);

  // flash GQA attention -> ctx (T, 4096) bf16 (overwrites hb; hidden is dead)
  // grid 1024: 128 16-row q-chunks x 8 head-groups, 4 blocks/CU
  attn_kernel<<<dim3(1024), blk, 0, stream>>>(qbf, ckv, cvT, ctx);

  // out = ctx@Wo -> fp32 d_out, direct store (512 blocks, full K per block)
  gemm_bt<3><<<dim3(32, 16), blk, 0, stream>>>(ctx, WoT, d_out, nullptr,
                                               positions);
}